// Round 1
// baseline (244.857 us; speedup 1.0000x reference)
//
#include <hip/hip_runtime.h>
#include <stdint.h>

typedef __attribute__((ext_vector_type(4))) float f32x4;
typedef __attribute__((ext_vector_type(8))) __bf16 bf16x8;
typedef __attribute__((ext_vector_type(4))) unsigned short u16x4;
typedef __attribute__((ext_vector_type(8))) unsigned short u16x8;

#define DEV __device__ __forceinline__

DEV unsigned short f2bf(float f) {
  union { float f; unsigned int u; } v; v.f = f;
  unsigned int r = v.u + 0x7fffu + ((v.u >> 16) & 1u);
  return (unsigned short)(r >> 16);
}

DEV void gl_lds16(const void* g, void* l) {
  __builtin_amdgcn_global_load_lds(
      (const __attribute__((address_space(1))) unsigned int*)g,
      (__attribute__((address_space(3))) unsigned int*)l, 16, 0, 0);
}

// ---------------- prep kernels ----------------

__global__ void prep_rope(float* __restrict__ costab, float* __restrict__ sintab) {
  int idx = blockIdx.x * 256 + threadIdx.x;     // 4096*64 total
  int n = idx >> 6, c = idx & 63, j = c >> 1;
  float inv = powf(10000.0f, -(float)(2 * j) / 64.0f);
  float ang = (float)n * inv;
  costab[idx] = cosf(ang);
  sintab[idx] = sinf(ang);
}

__global__ void prep_wtab(const float* __restrict__ gm, float* __restrict__ wtab) {
  int t = threadIdx.x;                           // 1024 threads: [2][512]
  int b = t >> 9, d = t & 511;
  wtab[t] = gm[b * 4096 + d] * powf(0.96f, (float)d);
}

__global__ void cvt_x(const float* __restrict__ x, unsigned short* __restrict__ xb) {
  size_t i8 = ((size_t)blockIdx.x * 256 + threadIdx.x) * 8;
  float4 a = *(const float4*)(x + i8);
  float4 b = *(const float4*)(x + i8 + 4);
  u16x8 o;
  o[0] = f2bf(a.x); o[1] = f2bf(a.y); o[2] = f2bf(a.z); o[3] = f2bf(a.w);
  o[4] = f2bf(b.x); o[5] = f2bf(b.y); o[6] = f2bf(b.z); o[7] = f2bf(b.w);
  *(u16x8*)(xb + i8) = o;
}

// 1024x1024 fp32 -> transposed bf16
__global__ void transpose_cvt(const float* __restrict__ src, unsigned short* __restrict__ dst) {
  __shared__ float tile[32][33];
  int tx = threadIdx.x & 31, ty = threadIdx.x >> 5;   // 32x8
  int c0 = blockIdx.x * 32, r0 = blockIdx.y * 32;
  #pragma unroll
  for (int j = 0; j < 4; j++)
    tile[ty + 8 * j][tx] = src[(size_t)(r0 + ty + 8 * j) * 1024 + c0 + tx];
  __syncthreads();
  #pragma unroll
  for (int j = 0; j < 4; j++)
    dst[(size_t)(c0 + ty + 8 * j) * 1024 + r0 + tx] = f2bf(tile[tx][ty + 8 * j]);
}

// ---------------- 128x128 GEMM, A(MxK) bf16 row-major, Bt(NxK) bf16 row-major ----------------
// EPI 0: qkv epilogue (rope+relu -> Qb,Kb row-major; relu -> Vt transposed)
// EPI 1: fc epilogue (+bias, fp32 out)
template<int EPI>
__global__ void __launch_bounds__(256, 2)
gemm128(const unsigned short* __restrict__ A,
        const unsigned short* __restrict__ Bt,
        unsigned short* __restrict__ q_out,
        unsigned short* __restrict__ k_out,
        unsigned short* __restrict__ vt_out,
        const float* __restrict__ costab,
        const float* __restrict__ sintab,
        float* __restrict__ f_out,
        const float* __restrict__ bias)
{
  constexpr int K = 1024;
  __shared__ char smem[32768];
  char* a_sm = smem;
  char* b_sm = smem + 16384;
  const int tid = threadIdx.x;
  const int lane = tid & 63;
  const int w = tid >> 6;
  const int wm = w >> 1, wn = w & 1;
  const int bm = blockIdx.x, bn = blockIdx.y;

  const f32x4 fz = {0.f, 0.f, 0.f, 0.f};
  f32x4 acc[4][4];
  #pragma unroll
  for (int i = 0; i < 4; i++)
    #pragma unroll
    for (int j = 0; j < 4; j++) acc[i][j] = fz;

  const unsigned short* Abase = A + (size_t)bm * 128 * K;
  const unsigned short* Bbase = Bt + (size_t)bn * 128 * K;

  for (int k0 = 0; k0 < K; k0 += 64) {
    __syncthreads();
    #pragma unroll
    for (int i = 0; i < 4; i++) {
      int tg = i * 256 + tid;
      int row = tg >> 3;
      int sl = (tg & 7) ^ (row & 7);            // pre-swizzled global source (m173 pattern)
      gl_lds16(Abase + (size_t)row * K + k0 + sl * 8, a_sm + tg * 16);
    }
    #pragma unroll
    for (int i = 0; i < 4; i++) {
      int tg = i * 256 + tid;
      int row = tg >> 3;
      int sl = (tg & 7) ^ (row & 7);
      gl_lds16(Bbase + (size_t)row * K + k0 + sl * 8, b_sm + tg * 16);
    }
    __syncthreads();
    #pragma unroll
    for (int ks = 0; ks < 2; ks++) {
      int kb = ks * 64 + ((lane >> 4) << 4);
      bf16x8 af[4], bfv[4];
      #pragma unroll
      for (int f = 0; f < 4; f++) {
        int ar = wm * 64 + f * 16 + (lane & 15);
        af[f] = *(const bf16x8*)(a_sm + ar * 128 + (kb ^ ((ar & 7) << 4)));
        int br = wn * 64 + f * 16 + (lane & 15);
        bfv[f] = *(const bf16x8*)(b_sm + br * 128 + (kb ^ ((br & 7) << 4)));
      }
      #pragma unroll
      for (int fm = 0; fm < 4; fm++)
        #pragma unroll
        for (int fn = 0; fn < 4; fn++)
          acc[fm][fn] = __builtin_amdgcn_mfma_f32_16x16x32_bf16(af[fm], bfv[fn], acc[fm][fn], 0, 0, 0);
    }
  }

  const int rbase = bm * 128 + wm * 64 + ((lane >> 4) << 2);
  const int cbase = bn * 128 + wn * 64;

  if constexpr (EPI == 0) {
    #pragma unroll
    for (int fn = 0; fn < 4; fn++) {
      int col = cbase + fn * 16 + (lane & 15);
      int which = col >> 10;                     // 0=Q 1=K 2=V
      int c = col & 1023;
      #pragma unroll
      for (int fm = 0; fm < 4; fm++) {
        int row0 = rbase + fm * 16;
        float vals[4];
        #pragma unroll
        for (int r = 0; r < 4; r++) vals[r] = acc[fm][fn][r];
        if (which < 2) {
          if (c < 64) {                          // wave-uniform per fragment
            #pragma unroll
            for (int r = 0; r < 4; r++) {
              float p = __shfl_xor(vals[r], 1);  // paired rope element (col^1)
              int n = (row0 + r) & 4095;
              float cs = costab[n * 64 + c];
              float sn = sintab[n * 64 + c];
              float rh = (c & 1) ? p : -p;
              vals[r] = vals[r] * cs + rh * sn;
            }
          }
          unsigned short* dst = (which == 0) ? q_out : k_out;
          #pragma unroll
          for (int r = 0; r < 4; r++) {
            float v = vals[r] > 0.f ? vals[r] : 0.f;
            dst[(size_t)(row0 + r) * 1024 + c] = f2bf(v);
          }
        } else {
          u16x4 sv;
          #pragma unroll
          for (int r = 0; r < 4; r++) {
            float v = vals[r] > 0.f ? vals[r] : 0.f;
            sv[r] = f2bf(v);
          }
          *(u16x4*)(vt_out + (size_t)c * 8192 + row0) = sv;   // V^T scatter (4 contiguous tokens)
        }
      }
    }
  } else {
    #pragma unroll
    for (int fn = 0; fn < 4; fn++) {
      int col = cbase + fn * 16 + (lane & 15);
      float bv = bias[col];
      #pragma unroll
      for (int fm = 0; fm < 4; fm++) {
        int row0 = rbase + fm * 16;
        #pragma unroll
        for (int r = 0; r < 4; r++)
          f_out[(size_t)(row0 + r) * 1024 + col] = acc[fm][fn][r] + bv;
      }
    }
  }
}

// ---------------- windowed decay attention ----------------
// per block: 64 queries (q0..q0+63), keys kv0=q0-256 .. q0+63 (320 rows), 8 waves.
__global__ void __launch_bounds__(512, 2)
attn_kernel(const unsigned short* __restrict__ Qb,
            const unsigned short* __restrict__ Kb,
            const unsigned short* __restrict__ Vt,
            const float* __restrict__ wtab,
            const float* __restrict__ att_mask,
            unsigned short* __restrict__ Yb)
{
  __shared__ char smem[49152];
  __shared__ float wl[320];
  char* k_sm = smem;            // [320][64] bf16, XOR-swizzled (40960 B)
  char* q_sm = smem + 40960;    // [64][64]  bf16, XOR-swizzled (8192 B)
  char* p_sm = smem;            // [64][320] bf16, XOR-swizzled (aliases k_sm)

  const int tid = threadIdx.x;
  const int lane = tid & 63;
  const int w = tid >> 6;
  const int q0 = blockIdx.x * 64;
  const int b = blockIdx.y;
  const int base = b * 4096;
  const int kv0 = q0 - 256;

  if (tid < 320) wl[tid] = wtab[b * 512 + tid];

  const int wq = w >> 2, wk = w & 3;            // 2x4 wave grid for phase 1
  const f32x4 fz = {0.f, 0.f, 0.f, 0.f};
  f32x4 sacc[2][5];
  #pragma unroll
  for (int i = 0; i < 2; i++)
    #pragma unroll
    for (int j = 0; j < 5; j++) sacc[i][j] = fz;

  // phase 1: S = Q K^T over c-chunks of 64
  for (int c0 = 0; c0 < 1024; c0 += 64) {
    __syncthreads();
    {
      int row = tid >> 3;
      int sl = (tid & 7) ^ (row & 7);
      gl_lds16(Qb + (size_t)(base + q0 + row) * 1024 + c0 + sl * 8, q_sm + tid * 16);
    }
    #pragma unroll
    for (int i = 0; i < 5; i++) {
      int tg = i * 512 + tid;
      int row = tg >> 3;
      int sl = (tg & 7) ^ (row & 7);
      int m = kv0 + row; m = m < 0 ? 0 : m;     // clamped rows get weight 0 later
      gl_lds16(Kb + (size_t)(base + m) * 1024 + c0 + sl * 8, k_sm + tg * 16);
    }
    __syncthreads();
    #pragma unroll
    for (int ks = 0; ks < 2; ks++) {
      int kb = ks * 64 + ((lane >> 4) << 4);
      bf16x8 af[2], bfv[5];
      #pragma unroll
      for (int f = 0; f < 2; f++) {
        int ar = wq * 32 + f * 16 + (lane & 15);
        af[f] = *(const bf16x8*)(q_sm + ar * 128 + (kb ^ ((ar & 7) << 4)));
      }
      #pragma unroll
      for (int f = 0; f < 5; f++) {
        int br = wk * 80 + f * 16 + (lane & 15);
        bfv[f] = *(const bf16x8*)(k_sm + br * 128 + (kb ^ ((br & 7) << 4)));
      }
      #pragma unroll
      for (int fm = 0; fm < 2; fm++)
        #pragma unroll
        for (int fj = 0; fj < 5; fj++)
          sacc[fm][fj] = __builtin_amdgcn_mfma_f32_16x16x32_bf16(af[fm], bfv[fj], sacc[fm][fj], 0, 0, 0);
    }
  }
  __syncthreads();

  // weight + bf16 -> P in LDS
  #pragma unroll
  for (int fm = 0; fm < 2; fm++) {
    #pragma unroll
    for (int fj = 0; fj < 5; fj++) {
      int jj = wk * 80 + fj * 16 + (lane & 15);
      int m = kv0 + jj;
      #pragma unroll
      for (int r = 0; r < 4; r++) {
        int i = wq * 32 + fm * 16 + ((lane >> 4) << 2) + r;
        int d = 256 + i - jj;                    // n - m
        float wgt = (d >= 0 && m >= 0) ? wl[d] : 0.f;
        *(unsigned short*)(p_sm + i * 640 + ((jj * 2) ^ ((i & 7) << 4))) =
            f2bf(sacc[fm][fj][r] * wgt);
      }
    }
  }
  __syncthreads();

  // phase 2: y = P @ V (V^T fragments from global)
  f32x4 yacc[4][8];
  #pragma unroll
  for (int i = 0; i < 4; i++)
    #pragma unroll
    for (int j = 0; j < 8; j++) yacc[i][j] = fz;

  for (int kt = 0; kt < 10; kt++) {
    int kb = kt * 64 + ((lane >> 4) << 4);
    bf16x8 pa[4], vb[8];
    #pragma unroll
    for (int f = 0; f < 4; f++) {
      int i = f * 16 + (lane & 15);
      pa[f] = *(const bf16x8*)(p_sm + i * 640 + (kb ^ ((i & 7) << 4)));
    }
    int kvi = kt * 32 + ((lane >> 4) << 3);
    int m = kv0 + kvi; m = m < 0 ? 0 : m;        // whole 8-group clamps together
    #pragma unroll
    for (int f = 0; f < 8; f++) {
      int col = w * 128 + f * 16 + (lane & 15);
      vb[f] = *(const bf16x8*)(Vt + (size_t)col * 8192 + base + m);
    }
    #pragma unroll
    for (int fm = 0; fm < 4; fm++)
      #pragma unroll
      for (int fn = 0; fn < 8; fn++)
        yacc[fm][fn] = __builtin_amdgcn_mfma_f32_16x16x32_bf16(pa[fm], vb[fn], yacc[fm][fn], 0, 0, 0);
  }

  #pragma unroll
  for (int fm = 0; fm < 4; fm++) {
    #pragma unroll
    for (int r = 0; r < 4; r++) {
      int n = q0 + fm * 16 + ((lane >> 4) << 2) + r;
      float am = att_mask[base + n];
      #pragma unroll
      for (int fn = 0; fn < 8; fn++) {
        int col = w * 128 + fn * 16 + (lane & 15);
        Yb[(size_t)(base + n) * 1024 + col] = f2bf(yacc[fm][fn][r] * am);
      }
    }
  }
}

// ---------------- launcher ----------------
extern "C" void kernel_launch(void* const* d_in, const int* in_sizes, int n_in,
                              void* d_out, int out_size, void* d_ws, size_t ws_size,
                              hipStream_t stream)
{
  (void)in_sizes; (void)n_in; (void)out_size;
  const float* x   = (const float*)d_in[0];
  const float* gm  = (const float*)d_in[1];
  const float* am  = (const float*)d_in[2];
  const float* wq  = (const float*)d_in[3];
  const float* wk  = (const float*)d_in[4];
  const float* wv  = (const float*)d_in[5];
  const float* fcw = (const float*)d_in[6];
  const float* fcb = (const float*)d_in[7];
  float* out = (float*)d_out;

  char* p = (char*)d_ws;
  unsigned short* xb    = (unsigned short*)p; p += (size_t)8192 * 1024 * 2;
  unsigned short* Qb    = (unsigned short*)p; p += (size_t)8192 * 1024 * 2;
  unsigned short* Kb    = (unsigned short*)p; p += (size_t)8192 * 1024 * 2;
  unsigned short* Vt    = (unsigned short*)p; p += (size_t)8192 * 1024 * 2;
  unsigned short* Ybuf  = (unsigned short*)p; p += (size_t)8192 * 1024 * 2;
  unsigned short* WqkvT = (unsigned short*)p; p += (size_t)3072 * 1024 * 2;
  unsigned short* FcwT  = (unsigned short*)p; p += (size_t)1024 * 1024 * 2;
  float* costab = (float*)p; p += (size_t)4096 * 64 * 4;
  float* sintab = (float*)p; p += (size_t)4096 * 64 * 4;
  float* wtab   = (float*)p; p += 4096;
  if ((size_t)(p - (char*)d_ws) > ws_size) return;   // ws too small: fail cleanly

  prep_rope<<<1024, 256, 0, stream>>>(costab, sintab);
  prep_wtab<<<1, 1024, 0, stream>>>(gm, wtab);
  cvt_x<<<4096, 256, 0, stream>>>(x, xb);
  transpose_cvt<<<dim3(32, 32), 256, 0, stream>>>(wq, WqkvT);
  transpose_cvt<<<dim3(32, 32), 256, 0, stream>>>(wk, WqkvT + (size_t)1024 * 1024);
  transpose_cvt<<<dim3(32, 32), 256, 0, stream>>>(wv, WqkvT + (size_t)2048 * 1024);
  transpose_cvt<<<dim3(32, 32), 256, 0, stream>>>(fcw, FcwT);

  gemm128<0><<<dim3(64, 24), 256, 0, stream>>>(xb, WqkvT, Qb, Kb, Vt, costab, sintab, nullptr, nullptr);
  attn_kernel<<<dim3(64, 2), 512, 0, stream>>>(Qb, Kb, Vt, wtab, am, Ybuf);
  gemm128<1><<<dim3(64, 8), 256, 0, stream>>>(Ybuf, FcwT, nullptr, nullptr, nullptr, nullptr, nullptr, out, fcb);
}